// Round 1
// baseline (440.263 us; speedup 1.0000x reference)
//
#include <hip/hip_runtime.h>

#define NSRC1 292864
#define NDST1 11264
#define NE1   281600
#define NDST2 1024
#define NE2   10240
// IN = H = 256, C = 47, K_concat = 512

typedef __bf16 bf16x8 __attribute__((ext_vector_type(8)));
typedef float  f32x4  __attribute__((ext_vector_type(4)));

__device__ __forceinline__ unsigned short f2bf(float f) {
    union { float f; unsigned u; } v; v.f = f;
    unsigned r = v.u + 0x7FFF + ((v.u >> 16) & 1);   // RNE
    return (unsigned short)(r >> 16);
}

__device__ __forceinline__ void acc4(float4& a, const float4& v) {
    a.x += v.x; a.y += v.y; a.z += v.z; a.w += v.w;
}

// ---------------------------------------------------------------------------
// Merged prep: blocks [0,1140) build CSR rowptrs for both graphs (1 thread
// per edge); blocks [1140,1172) transpose+cast weights to Wt[n][k] bf16.
// ---------------------------------------------------------------------------
__global__ __launch_bounds__(256) void prep_kernel(
    const int* __restrict__ dst1, const int* __restrict__ dst2,
    const float* __restrict__ Ws, const float* __restrict__ Wn,
    int* __restrict__ rp1, int* __restrict__ rp2,
    unsigned short* __restrict__ Wt)     // [256, 512] bf16 bits
{
    __shared__ float t[64][65];
    if (blockIdx.x < 1140) {
        const int tid = blockIdx.x * 256 + threadIdx.x;
        if (tid < NE1) {
            const int d  = dst1[tid];
            const int dp = (tid == 0) ? -1 : dst1[tid - 1];
            for (int j = dp + 1; j <= d; ++j) rp1[j] = tid;
            if (tid == NE1 - 1) for (int j = d + 1; j <= NDST1; ++j) rp1[j] = NE1;
        } else {
            const int e  = tid - NE1;
            const int d  = dst2[e];
            const int dp = (e == 0) ? -1 : dst2[e - 1];
            for (int j = dp + 1; j <= d; ++j) rp2[j] = e;
            if (e == NE2 - 1) for (int j = d + 1; j <= NDST2; ++j) rp2[j] = NE2;
        }
        return;
    }
    const int tileid = blockIdx.x - 1140;       // 0..31
    const int kb = (tileid & 7) * 64, nb = (tileid >> 3) * 64;
    const float* __restrict__ W = (kb < 256) ? Ws : Wn;
    const int kofs = (kb < 256) ? kb : kb - 256;
    const int c  = threadIdx.x & 63;
    const int r0 = threadIdx.x >> 6;
    #pragma unroll
    for (int i = 0; i < 16; ++i) {
        const int r = r0 + i * 4;
        t[r][c] = W[(size_t)(kofs + r) * 256 + nb + c];
    }
    __syncthreads();
    #pragma unroll
    for (int i = 0; i < 16; ++i) {
        const int r = r0 + i * 4;
        Wt[(size_t)(nb + r) * 512 + kb + c] = f2bf(t[c][r]);
    }
}

// ---------------------------------------------------------------------------
// Layer-1 aggregation fused with bf16 A-matrix build.
// Abf[d][0:256] = bf16(x[d]); Abf[d][256:512] = bf16(mean_neigh(d)).
// One dst per wave, 4 waves/block. Indices for up to 64 edges are fetched
// with ONE per-lane vector load and extracted via v_readlane, so no scalar
// memory latency sits on the gather critical path.
// ---------------------------------------------------------------------------
__global__ __launch_bounds__(256) void agg1_fused_kernel(
    const float* __restrict__ x,         // [NSRC1, 256]
    const int*   __restrict__ src_idx,   // [NE1]
    const int*   __restrict__ rowptr,    // [NDST1+1]
    unsigned short* __restrict__ Abf)    // [NDST1, 512] bf16 bits
{
    const int lane = threadIdx.x & 63;
    const int w    = threadIdx.x >> 6;
    const int d    = blockIdx.x * 4 + w;

    const int start = rowptr[d];
    const int end   = rowptr[d + 1];

    const float4* __restrict__ xcol = (const float4*)x + lane;  // row r -> xcol[r*64]

    // issue the self row early; it drains while we aggregate
    const float4 xv = xcol[(size_t)d * 64];

    float4 a0 = make_float4(0.f,0.f,0.f,0.f);
    float4 a1 = a0, a2 = a0, a3 = a0, a4 = a0, a5 = a0, a6 = a0, a7 = a0;

    for (int base = start; base < end; base += 64) {
        const int nb = (end - base < 64) ? (end - base) : 64;
        int my = (lane < nb) ? src_idx[base + lane] : 0;   // one vector load
        int j = 0;
        for (; j + 8 <= nb; j += 8) {
            const int s0 = __builtin_amdgcn_readlane(my, j + 0);
            const int s1 = __builtin_amdgcn_readlane(my, j + 1);
            const int s2 = __builtin_amdgcn_readlane(my, j + 2);
            const int s3 = __builtin_amdgcn_readlane(my, j + 3);
            const int s4 = __builtin_amdgcn_readlane(my, j + 4);
            const int s5 = __builtin_amdgcn_readlane(my, j + 5);
            const int s6 = __builtin_amdgcn_readlane(my, j + 6);
            const int s7 = __builtin_amdgcn_readlane(my, j + 7);
            const float4 v0 = xcol[(size_t)s0 * 64];
            const float4 v1 = xcol[(size_t)s1 * 64];
            const float4 v2 = xcol[(size_t)s2 * 64];
            const float4 v3 = xcol[(size_t)s3 * 64];
            const float4 v4 = xcol[(size_t)s4 * 64];
            const float4 v5 = xcol[(size_t)s5 * 64];
            const float4 v6 = xcol[(size_t)s6 * 64];
            const float4 v7 = xcol[(size_t)s7 * 64];
            acc4(a0, v0); acc4(a1, v1); acc4(a2, v2); acc4(a3, v3);
            acc4(a4, v4); acc4(a5, v5); acc4(a6, v6); acc4(a7, v7);
        }
        if (j + 4 <= nb) {
            const int s0 = __builtin_amdgcn_readlane(my, j + 0);
            const int s1 = __builtin_amdgcn_readlane(my, j + 1);
            const int s2 = __builtin_amdgcn_readlane(my, j + 2);
            const int s3 = __builtin_amdgcn_readlane(my, j + 3);
            const float4 v0 = xcol[(size_t)s0 * 64];
            const float4 v1 = xcol[(size_t)s1 * 64];
            const float4 v2 = xcol[(size_t)s2 * 64];
            const float4 v3 = xcol[(size_t)s3 * 64];
            acc4(a0, v0); acc4(a1, v1); acc4(a2, v2); acc4(a3, v3);
            j += 4;
        }
        for (; j < nb; ++j) {
            const int s = __builtin_amdgcn_readlane(my, j);
            acc4(a0, xcol[(size_t)s * 64]);
        }
    }
    acc4(a0, a1); acc4(a2, a3); acc4(a4, a5); acc4(a6, a7);
    acc4(a0, a2); acc4(a4, a6); acc4(a0, a4);

    const int deg = end - start;
    const float inv = 1.0f / (deg > 0 ? (float)deg : 1.0f);

    ushort4 nbv;
    nbv.x = f2bf(a0.x * inv); nbv.y = f2bf(a0.y * inv);
    nbv.z = f2bf(a0.z * inv); nbv.w = f2bf(a0.w * inv);
    *(ushort4*)(Abf + (size_t)d * 512 + 256 + lane * 4) = nbv;

    ushort4 sf;
    sf.x = f2bf(xv.x); sf.y = f2bf(xv.y); sf.z = f2bf(xv.z); sf.w = f2bf(xv.w);
    *(ushort4*)(Abf + (size_t)d * 512 + lane * 4) = sf;
}

// ---------------------------------------------------------------------------
// Layer-1 GEMM on MFMA: h = relu(Abf @ Wt^T + b), fp32 out.
// M=11264, N=256, K=512. BM=64, BN=64, BK=32; 4 waves, each 32x32.
// 704 blocks -> 92% last-block-wave efficiency (vs 69% at BM=128).
// ---------------------------------------------------------------------------
#define LDT 40   // LDS k-stride (bf16): 80B rows, 16B aligned, spreads banks

__global__ __launch_bounds__(256) void gemm1_mfma_kernel(
    const unsigned short* __restrict__ Abf,   // [NDST1, 512]
    const unsigned short* __restrict__ Wt,    // [256, 512]
    const float* __restrict__ bias,           // [256]
    float* __restrict__ h)                    // [NDST1, 256]
{
    __shared__ unsigned short As[64][LDT];
    __shared__ unsigned short Bs[64][LDT];

    const int tid  = threadIdx.x;
    const int lane = tid & 63;
    const int w    = tid >> 6;
    const int wm   = (w & 1) * 32;
    const int wn   = (w >> 1) * 32;
    const int mblk = blockIdx.x * 64;
    const int nblk = blockIdx.y * 64;

    const int r16 = lane & 15;
    const int k0  = (lane >> 4) * 8;

    f32x4 acc[2][2] = {};

    for (int kt = 0; kt < 512; kt += 32) {
        {
            const int r  = tid >> 2;          // 0..63
            const int kk = (tid & 3) * 8;
            *(uint4*)&As[r][kk] =
                *(const uint4*)(Abf + (size_t)(mblk + r) * 512 + kt + kk);
            *(uint4*)&Bs[r][kk] =
                *(const uint4*)(Wt + (size_t)(nblk + r) * 512 + kt + kk);
        }
        __syncthreads();

        bf16x8 bfrag[2];
        #pragma unroll
        for (int ni = 0; ni < 2; ++ni)
            bfrag[ni] = *(const bf16x8*)&Bs[wn + ni * 16 + r16][k0];
        #pragma unroll
        for (int mi = 0; mi < 2; ++mi) {
            const bf16x8 afrag = *(const bf16x8*)&As[wm + mi * 16 + r16][k0];
            #pragma unroll
            for (int ni = 0; ni < 2; ++ni)
                acc[mi][ni] = __builtin_amdgcn_mfma_f32_16x16x32_bf16(
                    afrag, bfrag[ni], acc[mi][ni], 0, 0, 0);
        }
        __syncthreads();
    }

    #pragma unroll
    for (int mi = 0; mi < 2; ++mi) {
        #pragma unroll
        for (int ni = 0; ni < 2; ++ni) {
            const int col = nblk + wn + ni * 16 + r16;
            const float bb = bias[col];
            #pragma unroll
            for (int r = 0; r < 4; ++r) {
                const int row = mblk + wm + mi * 16 + (lane >> 4) * 4 + r;
                const float v = acc[mi][ni][r] + bb;
                h[(size_t)row * 256 + col] = v > 0.f ? v : 0.f;
            }
        }
    }
}

// ---------------------------------------------------------------------------
// Fused layer 2: per wave, aggregate neighbor mean of h into LDS, stage the
// self row, then out[m] = h[m] @ Ws2 + hn @ Wn2 + b2 (lane = out column).
// Indices via one per-lane load + v_readlane (no scalar-mem latency).
// ---------------------------------------------------------------------------
__global__ __launch_bounds__(256) void layer2_kernel(
    const float* __restrict__ h,         // [NDST1, 256]
    const int*   __restrict__ src_idx,   // [NE2]
    const int*   __restrict__ rowptr,    // [NDST2+1]
    const float* __restrict__ Ws,        // [256, 47]
    const float* __restrict__ Wn,        // [256, 47]
    const float* __restrict__ b,         // [47]
    float* __restrict__ out)             // [NDST2, 47]
{
    __shared__ float hn[4][260];
    __shared__ float hs[4][260];

    const int lane = threadIdx.x & 63;
    const int w    = threadIdx.x >> 6;
    const int m    = blockIdx.x * 4 + w;

    const int start = rowptr[m];
    const int end   = rowptr[m + 1];

    const float4* __restrict__ hcol = (const float4*)h + lane;

    // self row early
    const float4 sv = hcol[(size_t)m * 64];

    float4 a0 = make_float4(0.f,0.f,0.f,0.f);
    float4 a1 = a0, a2 = a0, a3 = a0;

    for (int base = start; base < end; base += 64) {
        const int nb = (end - base < 64) ? (end - base) : 64;
        int my = (lane < nb) ? src_idx[base + lane] : 0;
        int j = 0;
        for (; j + 4 <= nb; j += 4) {
            const int s0 = __builtin_amdgcn_readlane(my, j + 0);
            const int s1 = __builtin_amdgcn_readlane(my, j + 1);
            const int s2 = __builtin_amdgcn_readlane(my, j + 2);
            const int s3 = __builtin_amdgcn_readlane(my, j + 3);
            const float4 v0 = hcol[(size_t)s0 * 64];
            const float4 v1 = hcol[(size_t)s1 * 64];
            const float4 v2 = hcol[(size_t)s2 * 64];
            const float4 v3 = hcol[(size_t)s3 * 64];
            acc4(a0, v0); acc4(a1, v1); acc4(a2, v2); acc4(a3, v3);
        }
        for (; j < nb; ++j) {
            const int s = __builtin_amdgcn_readlane(my, j);
            acc4(a0, hcol[(size_t)s * 64]);
        }
    }
    acc4(a0, a1); acc4(a2, a3); acc4(a0, a2);

    const int deg = end - start;
    const float inv = 1.0f / (deg > 0 ? (float)deg : 1.0f);
    a0.x *= inv; a0.y *= inv; a0.z *= inv; a0.w *= inv;
    *(float4*)&hn[w][lane * 4] = a0;
    *(float4*)&hs[w][lane * 4] = sv;
    __syncthreads();

    if (lane < 47) {
        float acc = b[lane];
        #pragma unroll 4
        for (int k = 0; k < 256; ++k) {
            acc += hs[w][k] * Ws[k * 47 + lane] + hn[w][k] * Wn[k * 47 + lane];
        }
        out[(size_t)m * 47 + lane] = acc;
    }
}

extern "C" void kernel_launch(void* const* d_in, const int* in_sizes, int n_in,
                              void* d_out, int out_size, void* d_ws, size_t ws_size,
                              hipStream_t stream) {
    const float* x    = (const float*)d_in[0];
    const int*   src1 = (const int*)  d_in[1];
    const int*   dst1 = (const int*)  d_in[2];
    const int*   src2 = (const int*)  d_in[3];
    const int*   dst2 = (const int*)  d_in[4];
    const float* Ws1  = (const float*)d_in[5];
    const float* Wn1  = (const float*)d_in[6];
    const float* b1   = (const float*)d_in[7];
    const float* Ws2  = (const float*)d_in[8];
    const float* Wn2  = (const float*)d_in[9];
    const float* b2   = (const float*)d_in[10];
    float* out = (float*)d_out;

    char* ws = (char*)d_ws;
    const size_t sz_Abf = (size_t)NDST1 * 512 * sizeof(unsigned short); // 11.5 MB
    const size_t sz_h   = (size_t)NDST1 * 256 * sizeof(float);          // 11.5 MB
    const size_t sz_Wt  = (size_t)256 * 512 * sizeof(unsigned short);   // 256 KB
    const size_t sz_rp1 = (size_t)(NDST1 + 2) * sizeof(int);
    unsigned short* Abf = (unsigned short*)(ws);
    float*          h   = (float*)(ws + sz_Abf);
    unsigned short* Wt  = (unsigned short*)(ws + sz_Abf + sz_h);
    int*            rp1 = (int*)(ws + sz_Abf + sz_h + sz_Wt);
    int*            rp2 = (int*)(ws + sz_Abf + sz_h + sz_Wt + sz_rp1);

    // rowptr (both graphs) + weight transpose, one launch
    prep_kernel<<<1172, 256, 0, stream>>>(dst1, dst2, Ws1, Wn1, rp1, rp2, Wt);
    // Layer 1 aggregation fused with bf16 A build
    agg1_fused_kernel<<<NDST1 / 4, 256, 0, stream>>>(x, src1, rp1, Abf);
    // Layer 1 MFMA GEMM + bias + relu
    dim3 g1(NDST1 / 64, 256 / 64);
    gemm1_mfma_kernel<<<g1, 256, 0, stream>>>(Abf, Wt, b1, h);
    // Layer 2: aggregation + output GEMM fused
    layer2_kernel<<<NDST2 / 4, 256, 0, stream>>>(h, src2, rp2, Ws2, Wn2, b2, out);
}